// Round 11
// baseline (145.504 us; speedup 1.0000x reference)
//
#include <hip/hip_runtime.h>

// ---------------------------------------------------------------------------
// MultiheadAttention (B=2, S=2048, E=1024, H=16, D=64, MAX_DIST=4, causal)
//   1. f2bf_all: one conversion kernel (x once; 4 weights)
//   2. proj3: kh=[bs][e], qh=[bs][e] (*0.125), vt=[e][bs]  (BK=64, swizzled)
//   3. flash attention v10: QB=128, 8-wave blocks (inner loop identical to
//      r9), split-K chunks <=8 k-tiles, LPT, 48KB LDS -> 3 blocks/CU
//      (24 waves/CU), bias-in-registers, swapped QK^T, XOR-swizzle, dbuf.
//   4. combine partials (up to 4-way) -> ao
//   5. out = ao @ Wo^T -> fp32 (64x128 tile, 512 blocks, BK=64)
// ---------------------------------------------------------------------------

using short8  = __attribute__((ext_vector_type(8))) short;
using floatx4 = __attribute__((ext_vector_type(4))) float;
using float4v = __attribute__((ext_vector_type(4))) float;
using ushort4v = __attribute__((ext_vector_type(4))) unsigned short;
using uint2v  = __attribute__((ext_vector_type(2))) unsigned int;

#define LOG2E 1.4426950408889634f

__device__ __forceinline__ unsigned short f2bf(float f) {
  unsigned u = __float_as_uint(f);
  return (unsigned short)((u + 0x7FFFu + ((u >> 16) & 1u)) >> 16);  // RNE
}
__device__ __forceinline__ float bf2f(unsigned short s) {
  return __uint_as_float(((unsigned)s) << 16);
}
__device__ __forceinline__ unsigned cvt_pk_bf16(float lo, float hi) {
  unsigned r;
  asm("v_cvt_pk_bf16_f32 %0, %1, %2" : "=v"(r) : "v"(lo), "v"(hi));
  return r;
}
__device__ __forceinline__ void gload_lds16(const void* g, void* l) {
  __builtin_amdgcn_global_load_lds(
      (const __attribute__((address_space(1))) unsigned int*)g,
      (__attribute__((address_space(3))) unsigned int*)l, 16, 0, 0);
}

// --------------------------- fp32 -> bf16 convert ---------------------------
__global__ void f2bf_all(const float* __restrict__ x, unsigned short* xo,
                         const float* __restrict__ w0, unsigned short* o0,
                         const float* __restrict__ w1, unsigned short* o1,
                         const float* __restrict__ w2, unsigned short* o2,
                         const float* __restrict__ w3, unsigned short* o3) {
  int i = blockIdx.x * 256 + threadIdx.x;  // 0 .. 2M-1 (float4 units)
  const float* in;
  unsigned short* out;
  int off;
  if (i < (1 << 20)) {
    in = x; out = xo; off = i;
  } else {
    int j = i - (1 << 20);
    int s = j >> 18;
    off = j & ((1 << 18) - 1);
    switch (s) {
      case 0: in = w0; out = o0; break;
      case 1: in = w1; out = o1; break;
      case 2: in = w2; out = o2; break;
      default: in = w3; out = o3; break;
    }
  }
  float4v v = ((const float4v*)in)[off];
  ushort4v o;
  o[0] = f2bf(v[0]); o[1] = f2bf(v[1]); o[2] = f2bf(v[2]); o[3] = f2bf(v[3]);
  ((ushort4v*)out)[off] = o;
}

// ------------------------- GEMM core (NT, BK=64, swz) ------------------------
template <int TM>
__device__ __forceinline__ void gemm_core64(
    const unsigned short* __restrict__ A, const unsigned short* __restrict__ B,
    void* __restrict__ Cv, int N, int K, int mBase, int nBase, float alpha,
    bool outbf, unsigned short* As, unsigned short* Bs) {
  const int tid = threadIdx.x;
  const int lane = tid & 63;
  const int w = tid >> 6;
  const int wr = w >> 1, wc = w & 1;
  const int lr = lane & 15, lg = lane >> 4;
  constexpr int NMF = TM / 32;

  floatx4 acc[NMF][4] = {};

  for (int k0 = 0; k0 < K; k0 += 64) {
#pragma unroll
    for (int i = 0; i < TM / 32; ++i) {
      int idx = i * 256 + tid;
      int row = idx >> 3, pc = idx & 7;
      int cl = pc ^ (row & 7);
      gload_lds16(A + (size_t)(mBase + row) * K + k0 + cl * 8, As + idx * 8);
    }
#pragma unroll
    for (int i = 0; i < 4; ++i) {
      int idx = i * 256 + tid;
      int row = idx >> 3, pc = idx & 7;
      int cl = pc ^ (row & 7);
      gload_lds16(B + (size_t)(nBase + row) * K + k0 + cl * 8, Bs + idx * 8);
    }
    __syncthreads();
#pragma unroll
    for (int c = 0; c < 2; ++c) {
      short8 af[NMF], bfr[4];
#pragma unroll
      for (int mf = 0; mf < NMF; ++mf) {
        int row = wr * (TM / 2) + mf * 16 + lr;
        af[mf] = *(const short8*)(As + row * 64 + (((c * 4 + lg) ^ (lr & 7)) * 8));
      }
#pragma unroll
      for (int nf = 0; nf < 4; ++nf) {
        int row = wc * 64 + nf * 16 + lr;
        bfr[nf] = *(const short8*)(Bs + row * 64 + (((c * 4 + lg) ^ (lr & 7)) * 8));
      }
#pragma unroll
      for (int mf = 0; mf < NMF; ++mf)
#pragma unroll
        for (int nf = 0; nf < 4; ++nf)
          acc[mf][nf] = __builtin_amdgcn_mfma_f32_16x16x32_bf16(
              af[mf], bfr[nf], acc[mf][nf], 0, 0, 0);
    }
    __syncthreads();
  }

#pragma unroll
  for (int mf = 0; mf < NMF; ++mf)
#pragma unroll
    for (int nf = 0; nf < 4; ++nf)
#pragma unroll
      for (int r = 0; r < 4; ++r) {
        size_t row = (size_t)mBase + wr * (TM / 2) + mf * 16 + lg * 4 + r;
        size_t col = (size_t)nBase + wc * 64 + nf * 16 + lr;
        float v = acc[mf][nf][r] * alpha;
        if (outbf)
          ((unsigned short*)Cv)[row * (size_t)N + col] = f2bf(v);
        else
          ((float*)Cv)[row * (size_t)N + col] = v;
      }
}

__global__ __launch_bounds__(256, 2) void proj3_kern(
    const unsigned short* __restrict__ xbf, const unsigned short* __restrict__ wkb,
    unsigned short* __restrict__ khb,
    const unsigned short* __restrict__ wqb, unsigned short* __restrict__ qhb,
    const unsigned short* __restrict__ wvb, unsigned short* __restrict__ vtb) {
  __shared__ alignas(16) unsigned short As[128 * 64];
  __shared__ alignas(16) unsigned short Bs[128 * 64];
  int z = blockIdx.z;
  if (z == 0)
    gemm_core64<128>(xbf, wkb, khb, 1024, 1024, blockIdx.y * 128,
                     blockIdx.x * 128, 1.0f, true, As, Bs);
  else if (z == 1)
    gemm_core64<128>(xbf, wqb, qhb, 1024, 1024, blockIdx.y * 128,
                     blockIdx.x * 128, 0.125f, true, As, Bs);
  else
    gemm_core64<128>(wvb, xbf, vtb, 4096, 1024, blockIdx.x * 128,
                     blockIdx.y * 128, 1.0f, true, As, Bs);
}

__global__ __launch_bounds__(256, 2) void gemm_out_kern(
    const unsigned short* __restrict__ A, const unsigned short* __restrict__ B,
    float* __restrict__ C) {
  __shared__ alignas(16) unsigned short As[64 * 64];
  __shared__ alignas(16) unsigned short Bs[128 * 64];
  gemm_core64<64>(A, B, C, 1024, 1024, blockIdx.y * 64, blockIdx.x * 128,
                  1.0f, false, As, Bs);
}

// ---------------------------- flash attention v10 ----------------------------
// Grid (32 hb, 38 units). Block = 512 threads = 8 waves; q-unit = 128 rows,
// wave w owns rows w*16..w*16+15. Unit = (qi, k-chunk) with chunks <= 8
// k-tiles; i<=5 run their whole causal span. LPT via encoded table.
#define ENC(qi, k0, k1, pp) ((qi) | ((k0) << 4) | ((k1) << 9) | ((pp) << 15))
__device__ const unsigned int UTAB[38] = {
    ENC(5, 0, 12, 63),  ENC(4, 0, 10, 63),  ENC(6, 0, 8, 0),
    ENC(7, 0, 8, 2),    ENC(7, 8, 16, 3),   ENC(8, 0, 8, 4),
    ENC(8, 8, 16, 5),   ENC(9, 0, 8, 7),    ENC(9, 8, 16, 8),
    ENC(10, 0, 8, 10),  ENC(10, 8, 16, 11), ENC(11, 0, 8, 13),
    ENC(11, 8, 16, 14), ENC(11, 16, 24, 15),ENC(12, 0, 8, 16),
    ENC(12, 8, 16, 17), ENC(12, 16, 24, 18),ENC(13, 0, 8, 20),
    ENC(13, 8, 16, 21), ENC(13, 16, 24, 22),ENC(14, 0, 8, 24),
    ENC(14, 8, 16, 25), ENC(14, 16, 24, 26),ENC(15, 0, 8, 28),
    ENC(15, 8, 16, 29), ENC(15, 16, 24, 30),ENC(15, 24, 32, 31),
    ENC(3, 0, 8, 63),   ENC(2, 0, 6, 63),   ENC(6, 8, 14, 1),
    ENC(10, 16, 22, 12),ENC(14, 24, 30, 27),ENC(1, 0, 4, 63),
    ENC(9, 16, 20, 9),  ENC(13, 24, 28, 23),ENC(0, 0, 2, 63),
    ENC(8, 16, 18, 6),  ENC(12, 24, 26, 19)};

__global__ __launch_bounds__(512, 6) void attn_kern(
    const unsigned short* __restrict__ qh,   // [4096][1024], pre-scaled
    const unsigned short* __restrict__ kh,   // [4096][1024]
    const unsigned short* __restrict__ vt,   // [1024][4096]
    const float* __restrict__ pp,            // [64][9]
    unsigned short* __restrict__ ao,         // [4096][1024]
    unsigned short* __restrict__ opart,      // [1024][128][64] bf16 unnorm
    float* __restrict__ mbuf,                // [1024][128]
    float* __restrict__ lbuf) {              // [1024][128]
  __shared__ alignas(16) char smem[49152];
  // Region A (0..16K): Q[128][64] prologue -> K1(8K)+V1(8K) steady state
  // Region B (16..32K): K0(8K)+V0(8K)
  // Region C (32..48K): Ps 8x2K; prologue overlay ppS(2304B)+biasT(3072B)
  unsigned short* QA  = (unsigned short*)smem;
  unsigned short* Ks1 = (unsigned short*)smem;
  unsigned short* Vs1 = (unsigned short*)(smem + 8192);
  unsigned short* Ks0 = (unsigned short*)(smem + 16384);
  unsigned short* Vs0 = (unsigned short*)(smem + 24576);
  unsigned short* Ps  = (unsigned short*)(smem + 32768);
  float* ppS   = (float*)(smem + 32768);   // [9][64], prologue only
  float* biasT = (float*)(smem + 35072);   // [128][6], prologue only

  const int tid = threadIdx.x;
  const int lane = tid & 63;
  const int w = tid >> 6;   // 0..7, owns q rows w*16..w*16+15
  const int lr = lane & 15, lg = lane >> 4;
  const int hb = blockIdx.x;
  const int h = hb & 15, b = hb >> 4;

  const unsigned e = UTAB[blockIdx.y];
  const int qi = e & 15;
  const int k0t = (e >> 4) & 31;
  const int k1t = (e >> 9) & 63;
  const int pofs = (e >> 15) & 63;
  const bool partial = (pofs != 63);
  const int qbase = qi << 7;
  const size_t bsQ = (size_t)b * 2048 + qbase;

  const unsigned short* khB = kh + ((size_t)b * 2048) * 1024 + h * 64;
  const unsigned short* vtB = vt + ((size_t)h * 64) * 4096 + b * 2048;

  auto stage_kv = [&](int kbase, unsigned short* Kd, unsigned short* Vd) {
    int row = tid >> 3, pc = tid & 7;
    int cl = pc ^ (row & 7);  // pre-swizzled global source
    gload_lds16(khB + ((size_t)(kbase + row) << 10) + cl * 8, Kd + tid * 8);
    gload_lds16(vtB + ((size_t)row << 12) + kbase + cl * 8, Vd + tid * 8);
  };

  // prologue: stage Q (128 rows, linear), pp table, first K/V tile
#pragma unroll
  for (int t = 0; t < 2; ++t) {
    int idx = t * 512 + tid;
    int row = idx >> 3, c8 = (idx & 7) * 8;
    gload_lds16(qh + (bsQ + row) * 1024 + h * 64 + c8, QA + idx * 8);
  }
  for (int idx = tid; idx < 576; idx += 512) {
    int r = idx >> 6, d = idx & 63;
    ppS[r * 64 + d] = pp[d * 9 + r];
  }
  stage_kv(k0t * 64, Ks0, Vs0);
  __syncthreads();

  // Q fragments (B-operand): lane holds Q[q = w*16+lr][d = c*32+lg*8+j]
  const int qrowL = w * 16 + lr;
  short8 aq[2];
#pragma unroll
  for (int c = 0; c < 2; ++c)
    aq[c] = *(const short8*)(QA + qrowL * 64 + c * 32 + lg * 8);

  // rel-pos bias (buckets 4..8 only; 0..3 causally dead)
  for (int idx = tid; idx < 640; idx += 512) {
    int row = idx / 5, rr = idx - row * 5;
    const unsigned short* qrow = QA + row * 64;
    const float* pr = ppS + (rr + 4) * 64;
    float s = 0.f;
#pragma unroll
    for (int d8 = 0; d8 < 8; ++d8) {
      short8 qv = *(const short8*)(qrow + d8 * 8);
#pragma unroll
      for (int j = 0; j < 8; ++j)
        s += bf2f((unsigned short)qv[j]) * pr[d8 * 8 + j];
    }
    biasT[row * 6 + rr] = s;
  }
  __syncthreads();

  const float b4 = biasT[qrowL * 6 + 0];
  const float b5 = biasT[qrowL * 6 + 1];
  const float b6 = biasT[qrowL * 6 + 2];
  const float b7 = biasT[qrowL * 6 + 3];
  const float b8 = biasT[qrowL * 6 + 4];
  __syncthreads();  // Q/ppS/biasT dead -> regions A and C recyclable

  const int q_glob = qbase + w * 16 + lr;
  const int wqtop = qbase + w * 16 + 15;  // wave's highest q row
  unsigned short* Pw = Ps + w * 1024;

  float m_run = -1e30f, l_run = 0.f;
  floatx4 o[4] = {};

  for (int kt = k0t; kt < k1t; ++kt) {
    const int kbase = kt * 64;
    const int cur = (kt - k0t) & 1;
    unsigned short* Kc = cur ? Ks1 : Ks0;
    unsigned short* Vc = cur ? Vs1 : Vs0;
    if (kt + 1 < k1t)
      stage_kv(kbase + 64, cur ? Ks0 : Ks1, cur ? Vs0 : Vs1);  // prefetch

    if (kbase <= wqtop) {  // wave has live work in this tile
      // S^T = K @ Q^T : lane holds S[k = kf*16+lg*4+r][q = w*16+lr]
      floatx4 sa[4] = {};
      __builtin_amdgcn_s_setprio(1);
#pragma unroll
      for (int kf = 0; kf < 4; ++kf)
#pragma unroll
        for (int c = 0; c < 2; ++c) {
          int row = kf * 16 + lr;
          short8 ak = *(const short8*)(Kc + row * 64 +
                                       (((c * 4 + lg) ^ (lr & 7)) * 8));
          sa[kf] = __builtin_amdgcn_mfma_f32_16x16x32_bf16(ak, aq[c], sa[kf],
                                                           0, 0, 0);
        }
      __builtin_amdgcn_s_setprio(0);

      // bias + causal mask (registers only)
      float bext;
      if (qbase + w * 16 >= kbase + 67) {
        bext = b8;
      } else {
        bext = 0.f;
#pragma unroll
        for (int kf = 0; kf < 4; ++kf)
#pragma unroll
          for (int r = 0; r < 4; ++r) {
            int dq = q_glob - (kbase + kf * 16 + lg * 4 + r);
            float bb = (dq >= 4) ? b8
                     : (dq == 0 ? b4 : (dq == 1 ? b5 : (dq == 2 ? b6 : b7)));
            sa[kf][r] = (dq < 0) ? -1e30f : (sa[kf][r] + bb);
          }
      }

      // online softmax with defer-max (THR=8)
      float mx = -1e30f;
#pragma unroll
      for (int kf = 0; kf < 4; ++kf)
#pragma unroll
        for (int r = 0; r < 4; ++r) mx = fmaxf(mx, sa[kf][r]);
      mx += bext;
      mx = fmaxf(mx, __shfl_xor(mx, 16, 64));
      mx = fmaxf(mx, __shfl_xor(mx, 32, 64));
      if (__any(mx > m_run + 8.f)) {
        float mn = fmaxf(m_run, mx);
        float al = __builtin_amdgcn_exp2f((m_run - mn) * LOG2E);
        m_run = mn;
        l_run *= al;
        float alo[4];
#pragma unroll
        for (int r = 0; r < 4; ++r) alo[r] = __shfl(al, lg * 4 + r, 64);
#pragma unroll
        for (int df = 0; df < 4; ++df)
#pragma unroll
          for (int r = 0; r < 4; ++r) o[df][r] *= alo[r];
      }

      const float c1 = (bext - m_run) * LOG2E;
      float rs = 0.f;
#pragma unroll
      for (int kf = 0; kf < 4; ++kf) {
        float p0 = __builtin_amdgcn_exp2f(fmaf(sa[kf][0], LOG2E, c1));
        float p1 = __builtin_amdgcn_exp2f(fmaf(sa[kf][1], LOG2E, c1));
        float p2 = __builtin_amdgcn_exp2f(fmaf(sa[kf][2], LOG2E, c1));
        float p3 = __builtin_amdgcn_exp2f(fmaf(sa[kf][3], LOG2E, c1));
        rs += (p0 + p1) + (p2 + p3);
        uint2v pk;
        pk[0] = cvt_pk_bf16(p0, p1);
        pk[1] = cvt_pk_bf16(p2, p3);
        int phys = (kf * 2 + (lg >> 1)) ^ (lr & 7);
        *(uint2v*)(Pw + lr * 64 + phys * 8 + (lg & 1) * 4) = pk;
      }
      rs += __shfl_xor(rs, 16, 64);
      rs += __shfl_xor(rs, 32, 64);
      l_run += rs;

      // O += P @ V
      __builtin_amdgcn_s_setprio(1);
#pragma unroll
      for (int c = 0; c < 2; ++c) {
        short8 pa = *(const short8*)(Pw + lr * 64 +
                                     (((c * 4 + lg) ^ (lr & 7)) * 8));
#pragma unroll
        for (int df = 0; df < 4; ++df) {
          int row = df * 16 + lr;
          short8 bv = *(const short8*)(Vc + row * 64 +
                                       (((c * 4 + lg) ^ (lr & 7)) * 8));
          o[df] = __builtin_amdgcn_mfma_f32_16x16x32_bf16(pa, bv, o[df],
                                                          0, 0, 0);
        }
      }
      __builtin_amdgcn_s_setprio(0);
    }
    __syncthreads();  // drains prefetch vmem + guards buffer swap
  }

  // epilogue: lane holds O[q = w*16+lg*4+r][d = df*16+lr]
  if (!partial) {
    float rl[4];
#pragma unroll
    for (int r = 0; r < 4; ++r)
      rl[r] = __builtin_amdgcn_rcpf(__shfl(l_run, lg * 4 + r, 64));
    const size_t outRow0 = bsQ + w * 16 + lg * 4;
#pragma unroll
    for (int df = 0; df < 4; ++df)
#pragma unroll
      for (int r = 0; r < 4; ++r)
        ao[(outRow0 + r) * 1024 + h * 64 + df * 16 + lr] =
            f2bf(o[df][r] * rl[r]);
  } else {
    const int pid = hb * 32 + pofs;
    unsigned short* op = opart + (size_t)pid * 8192;
#pragma unroll
    for (int df = 0; df < 4; ++df)
#pragma unroll
      for (int r = 0; r < 4; ++r)
        op[(w * 16 + lg * 4 + r) * 64 + df * 16 + lr] = f2bf(o[df][r]);
    if (lg == 0) {
      mbuf[pid * 128 + w * 16 + lr] = m_run;
      lbuf[pid * 128 + w * 16 + lr] = l_run;
    }
  }
}

// ------------------------------ combine partials -----------------------------
// One block per (hb, i=6..15): merge nchunk partials into ao rows [i*128,+128).
__global__ void combine_kern(const unsigned short* __restrict__ opart,
                             const float* __restrict__ mbuf,
                             const float* __restrict__ lbuf,
                             unsigned short* __restrict__ ao) {
  const unsigned char NC[10] = {2, 2, 3, 3, 3, 3, 4, 4, 4, 4};
  const unsigned char PB[10] = {0, 2, 4, 7, 10, 13, 16, 20, 24, 28};
  const int bx = blockIdx.x;        // 0..319
  const int hb = bx / 10, ii = bx - hb * 10;
  const int i = 6 + ii;
  const int b = hb >> 4, h = hb & 15;
  const int nc = NC[ii];
  const int pid0 = hb * 32 + PB[ii];
  const int row = threadIdx.x >> 1;          // 0..127
  const int colg = (threadIdx.x & 1) * 32;   // 0 or 32

  float m[4], l[4];
  float M = -1e30f;
  for (int c = 0; c < nc; ++c) {
    m[c] = mbuf[(pid0 + c) * 128 + row];
    l[c] = lbuf[(pid0 + c) * 128 + row];
    M = fmaxf(M, m[c]);
  }
  float s[4], lsum = 0.f;
  for (int c = 0; c < nc; ++c) {
    s[c] = __builtin_amdgcn_exp2f((m[c] - M) * LOG2E);
    lsum = fmaf(l[c], s[c], lsum);
  }
  const float linv = 1.f / lsum;

  unsigned short* dst =
      ao + ((size_t)b * 2048 + i * 128 + row) * 1024 + h * 64 + colg;
#pragma unroll
  for (int t = 0; t < 4; ++t) {
    float acc[8] = {};
    for (int c = 0; c < nc; ++c) {
      const unsigned short* Oc =
          opart + (size_t)(pid0 + c) * 8192 + row * 64 + colg + t * 8;
      short8 a = *(const short8*)Oc;
#pragma unroll
      for (int j = 0; j < 8; ++j)
        acc[j] = fmaf(bf2f((unsigned short)a[j]), s[c], acc[j]);
    }
    short8 ov;
#pragma unroll
    for (int j = 0; j < 8; ++j) ov[j] = (short)f2bf(acc[j] * linv);
    *(short8*)(dst + t * 8) = ov;
  }
}

// --------------------------------- launcher ---------------------------------
extern "C" void kernel_launch(void* const* d_in, const int* in_sizes, int n_in,
                              void* d_out, int out_size, void* d_ws,
                              size_t ws_size, hipStream_t stream) {
  const float* k_in = (const float*)d_in[0];  // k == v == q (same x tensor)
  const float* Wk = (const float*)d_in[3];
  const float* Wv = (const float*)d_in[4];
  const float* Wq = (const float*)d_in[5];
  const float* Wo = (const float*)d_in[6];
  const float* pp = (const float*)d_in[7];

  const size_t NX = 4096u * 1024u;
  const size_t NW = 1024u * 1024u;
  unsigned short* ws = (unsigned short*)d_ws;
  unsigned short* xbf = ws;
  unsigned short* wkb = xbf + NX;
  unsigned short* wvb = wkb + NW;
  unsigned short* wqb = wvb + NW;
  unsigned short* wob = wqb + NW;
  unsigned short* khb = wob + NW;
  unsigned short* vtb = khb + NX;
  unsigned short* qhb = vtb + NX;
  unsigned short* aob = qhb + NX;
  unsigned short* opart = aob + NX;   // 1024 x 8192 bf16 = 16 MB (ends @64MB)
  // m/l buffers alias the xbf region (dead after proj3): 1024*128 f32 each
  float* mbuf = (float*)xbf;
  float* lbuf = mbuf + 1024 * 128;

  (void)in_sizes; (void)n_in; (void)out_size; (void)ws_size;

  f2bf_all<<<dim3(8192), dim3(256), 0, stream>>>(
      k_in, xbf, Wk, wkb, Wv, wvb, Wq, wqb, Wo, wob);

  proj3_kern<<<dim3(8, 32, 3), dim3(256), 0, stream>>>(
      xbf, wkb, khb, wqb, qhb, wvb, vtb);

  attn_kern<<<dim3(32, 38), dim3(512), 0, stream>>>(qhb, khb, vtb, pp, aob,
                                                    opart, mbuf, lbuf);
  combine_kern<<<dim3(320), dim3(256), 0, stream>>>(opart, mbuf, lbuf, aob);

  gemm_out_kern<<<dim3(8, 64), dim3(256), 0, stream>>>(aob, wob, (float*)d_out);
}

// Round 12
// 112.457 us; speedup vs baseline: 1.2939x; 1.2939x over previous
//
#include <hip/hip_runtime.h>

// ---------------------------------------------------------------------------
// MultiheadAttention (B=2, S=2048, E=1024, H=16, D=64, MAX_DIST=4, causal)
//   1. f2bf_all: one conversion kernel (x once; 4 weights)
//   2. proj3: kh=[bs][e], qh=[bs][e] (*0.125), vt=[e][bs]  (BK=64, swizzled)
//   3. flash attention v10b: QB=128, 8-wave blocks, split-K chunks <=8,
//      LPT, 48KB LDS -> 3 blocks/CU. launch_bounds(512,4): r11's (512,6)
//      forced VGPR=40 -> scratch spills (94MB FETCH). Now ~64 VGPR, no spill.
//   4. combine partials (up to 4-way) -> ao
//   5. out = ao @ Wo^T -> fp32 (64x128 tile, 512 blocks, BK=64)
// ---------------------------------------------------------------------------

using short8  = __attribute__((ext_vector_type(8))) short;
using floatx4 = __attribute__((ext_vector_type(4))) float;
using float4v = __attribute__((ext_vector_type(4))) float;
using ushort4v = __attribute__((ext_vector_type(4))) unsigned short;
using uint2v  = __attribute__((ext_vector_type(2))) unsigned int;

#define LOG2E 1.4426950408889634f

__device__ __forceinline__ unsigned short f2bf(float f) {
  unsigned u = __float_as_uint(f);
  return (unsigned short)((u + 0x7FFFu + ((u >> 16) & 1u)) >> 16);  // RNE
}
__device__ __forceinline__ float bf2f(unsigned short s) {
  return __uint_as_float(((unsigned)s) << 16);
}
__device__ __forceinline__ unsigned cvt_pk_bf16(float lo, float hi) {
  unsigned r;
  asm("v_cvt_pk_bf16_f32 %0, %1, %2" : "=v"(r) : "v"(lo), "v"(hi));
  return r;
}
__device__ __forceinline__ void gload_lds16(const void* g, void* l) {
  __builtin_amdgcn_global_load_lds(
      (const __attribute__((address_space(1))) unsigned int*)g,
      (__attribute__((address_space(3))) unsigned int*)l, 16, 0, 0);
}

// --------------------------- fp32 -> bf16 convert ---------------------------
__global__ void f2bf_all(const float* __restrict__ x, unsigned short* xo,
                         const float* __restrict__ w0, unsigned short* o0,
                         const float* __restrict__ w1, unsigned short* o1,
                         const float* __restrict__ w2, unsigned short* o2,
                         const float* __restrict__ w3, unsigned short* o3) {
  int i = blockIdx.x * 256 + threadIdx.x;  // 0 .. 2M-1 (float4 units)
  const float* in;
  unsigned short* out;
  int off;
  if (i < (1 << 20)) {
    in = x; out = xo; off = i;
  } else {
    int j = i - (1 << 20);
    int s = j >> 18;
    off = j & ((1 << 18) - 1);
    switch (s) {
      case 0: in = w0; out = o0; break;
      case 1: in = w1; out = o1; break;
      case 2: in = w2; out = o2; break;
      default: in = w3; out = o3; break;
    }
  }
  float4v v = ((const float4v*)in)[off];
  ushort4v o;
  o[0] = f2bf(v[0]); o[1] = f2bf(v[1]); o[2] = f2bf(v[2]); o[3] = f2bf(v[3]);
  ((ushort4v*)out)[off] = o;
}

// ------------------------- GEMM core (NT, BK=64, swz) ------------------------
template <int TM>
__device__ __forceinline__ void gemm_core64(
    const unsigned short* __restrict__ A, const unsigned short* __restrict__ B,
    void* __restrict__ Cv, int N, int K, int mBase, int nBase, float alpha,
    bool outbf, unsigned short* As, unsigned short* Bs) {
  const int tid = threadIdx.x;
  const int lane = tid & 63;
  const int w = tid >> 6;
  const int wr = w >> 1, wc = w & 1;
  const int lr = lane & 15, lg = lane >> 4;
  constexpr int NMF = TM / 32;

  floatx4 acc[NMF][4] = {};

  for (int k0 = 0; k0 < K; k0 += 64) {
#pragma unroll
    for (int i = 0; i < TM / 32; ++i) {
      int idx = i * 256 + tid;
      int row = idx >> 3, pc = idx & 7;
      int cl = pc ^ (row & 7);
      gload_lds16(A + (size_t)(mBase + row) * K + k0 + cl * 8, As + idx * 8);
    }
#pragma unroll
    for (int i = 0; i < 4; ++i) {
      int idx = i * 256 + tid;
      int row = idx >> 3, pc = idx & 7;
      int cl = pc ^ (row & 7);
      gload_lds16(B + (size_t)(nBase + row) * K + k0 + cl * 8, Bs + idx * 8);
    }
    __syncthreads();
#pragma unroll
    for (int c = 0; c < 2; ++c) {
      short8 af[NMF], bfr[4];
#pragma unroll
      for (int mf = 0; mf < NMF; ++mf) {
        int row = wr * (TM / 2) + mf * 16 + lr;
        af[mf] = *(const short8*)(As + row * 64 + (((c * 4 + lg) ^ (lr & 7)) * 8));
      }
#pragma unroll
      for (int nf = 0; nf < 4; ++nf) {
        int row = wc * 64 + nf * 16 + lr;
        bfr[nf] = *(const short8*)(Bs + row * 64 + (((c * 4 + lg) ^ (lr & 7)) * 8));
      }
#pragma unroll
      for (int mf = 0; mf < NMF; ++mf)
#pragma unroll
        for (int nf = 0; nf < 4; ++nf)
          acc[mf][nf] = __builtin_amdgcn_mfma_f32_16x16x32_bf16(
              af[mf], bfr[nf], acc[mf][nf], 0, 0, 0);
    }
    __syncthreads();
  }

#pragma unroll
  for (int mf = 0; mf < NMF; ++mf)
#pragma unroll
    for (int nf = 0; nf < 4; ++nf)
#pragma unroll
      for (int r = 0; r < 4; ++r) {
        size_t row = (size_t)mBase + wr * (TM / 2) + mf * 16 + lg * 4 + r;
        size_t col = (size_t)nBase + wc * 64 + nf * 16 + lr;
        float v = acc[mf][nf][r] * alpha;
        if (outbf)
          ((unsigned short*)Cv)[row * (size_t)N + col] = f2bf(v);
        else
          ((float*)Cv)[row * (size_t)N + col] = v;
      }
}

__global__ __launch_bounds__(256, 2) void proj3_kern(
    const unsigned short* __restrict__ xbf, const unsigned short* __restrict__ wkb,
    unsigned short* __restrict__ khb,
    const unsigned short* __restrict__ wqb, unsigned short* __restrict__ qhb,
    const unsigned short* __restrict__ wvb, unsigned short* __restrict__ vtb) {
  __shared__ alignas(16) unsigned short As[128 * 64];
  __shared__ alignas(16) unsigned short Bs[128 * 64];
  int z = blockIdx.z;
  if (z == 0)
    gemm_core64<128>(xbf, wkb, khb, 1024, 1024, blockIdx.y * 128,
                     blockIdx.x * 128, 1.0f, true, As, Bs);
  else if (z == 1)
    gemm_core64<128>(xbf, wqb, qhb, 1024, 1024, blockIdx.y * 128,
                     blockIdx.x * 128, 0.125f, true, As, Bs);
  else
    gemm_core64<128>(wvb, xbf, vtb, 4096, 1024, blockIdx.x * 128,
                     blockIdx.y * 128, 1.0f, true, As, Bs);
}

__global__ __launch_bounds__(256, 2) void gemm_out_kern(
    const unsigned short* __restrict__ A, const unsigned short* __restrict__ B,
    float* __restrict__ C) {
  __shared__ alignas(16) unsigned short As[64 * 64];
  __shared__ alignas(16) unsigned short Bs[128 * 64];
  gemm_core64<64>(A, B, C, 1024, 1024, blockIdx.y * 64, blockIdx.x * 128,
                  1.0f, false, As, Bs);
}

// ---------------------------- flash attention v10b ---------------------------
// Grid (32 hb, 38 units). Block = 512 threads = 8 waves; q-unit = 128 rows,
// wave w owns rows w*16..w*16+15. Unit = (qi, k-chunk) with chunks <= 8
// k-tiles; i<=5 run their whole causal span. LPT via encoded table.
#define ENC(qi, k0, k1, pp) ((qi) | ((k0) << 4) | ((k1) << 9) | ((pp) << 15))
__device__ const unsigned int UTAB[38] = {
    ENC(5, 0, 12, 63),  ENC(4, 0, 10, 63),  ENC(6, 0, 8, 0),
    ENC(7, 0, 8, 2),    ENC(7, 8, 16, 3),   ENC(8, 0, 8, 4),
    ENC(8, 8, 16, 5),   ENC(9, 0, 8, 7),    ENC(9, 8, 16, 8),
    ENC(10, 0, 8, 10),  ENC(10, 8, 16, 11), ENC(11, 0, 8, 13),
    ENC(11, 8, 16, 14), ENC(11, 16, 24, 15),ENC(12, 0, 8, 16),
    ENC(12, 8, 16, 17), ENC(12, 16, 24, 18),ENC(13, 0, 8, 20),
    ENC(13, 8, 16, 21), ENC(13, 16, 24, 22),ENC(14, 0, 8, 24),
    ENC(14, 8, 16, 25), ENC(14, 16, 24, 26),ENC(15, 0, 8, 28),
    ENC(15, 8, 16, 29), ENC(15, 16, 24, 30),ENC(15, 24, 32, 31),
    ENC(3, 0, 8, 63),   ENC(2, 0, 6, 63),   ENC(6, 8, 14, 1),
    ENC(10, 16, 22, 12),ENC(14, 24, 30, 27),ENC(1, 0, 4, 63),
    ENC(9, 16, 20, 9),  ENC(13, 24, 28, 23),ENC(0, 0, 2, 63),
    ENC(8, 16, 18, 6),  ENC(12, 24, 26, 19)};

__global__ __launch_bounds__(512, 4) void attn_kern(
    const unsigned short* __restrict__ qh,   // [4096][1024], pre-scaled
    const unsigned short* __restrict__ kh,   // [4096][1024]
    const unsigned short* __restrict__ vt,   // [1024][4096]
    const float* __restrict__ pp,            // [64][9]
    unsigned short* __restrict__ ao,         // [4096][1024]
    unsigned short* __restrict__ opart,      // [1024][128][64] bf16 unnorm
    float* __restrict__ mbuf,                // [1024][128]
    float* __restrict__ lbuf) {              // [1024][128]
  __shared__ alignas(16) char smem[49152];
  // Region A (0..16K): Q[128][64] prologue -> K1(8K)+V1(8K) steady state
  // Region B (16..32K): K0(8K)+V0(8K)
  // Region C (32..48K): Ps 8x2K; prologue overlay ppS(2304B)+biasT(3072B)
  unsigned short* QA  = (unsigned short*)smem;
  unsigned short* Ks1 = (unsigned short*)smem;
  unsigned short* Vs1 = (unsigned short*)(smem + 8192);
  unsigned short* Ks0 = (unsigned short*)(smem + 16384);
  unsigned short* Vs0 = (unsigned short*)(smem + 24576);
  unsigned short* Ps  = (unsigned short*)(smem + 32768);
  float* ppS   = (float*)(smem + 32768);   // [9][64], prologue only
  float* biasT = (float*)(smem + 35072);   // [128][6], prologue only

  const int tid = threadIdx.x;
  const int lane = tid & 63;
  const int w = tid >> 6;   // 0..7, owns q rows w*16..w*16+15
  const int lr = lane & 15, lg = lane >> 4;
  const int hb = blockIdx.x;
  const int h = hb & 15, b = hb >> 4;

  const unsigned e = UTAB[blockIdx.y];
  const int qi = e & 15;
  const int k0t = (e >> 4) & 31;
  const int k1t = (e >> 9) & 63;
  const int pofs = (e >> 15) & 63;
  const bool partial = (pofs != 63);
  const int qbase = qi << 7;
  const size_t bsQ = (size_t)b * 2048 + qbase;

  const unsigned short* khB = kh + ((size_t)b * 2048) * 1024 + h * 64;
  const unsigned short* vtB = vt + ((size_t)h * 64) * 4096 + b * 2048;

  auto stage_kv = [&](int kbase, unsigned short* Kd, unsigned short* Vd) {
    int row = tid >> 3, pc = tid & 7;
    int cl = pc ^ (row & 7);  // pre-swizzled global source
    gload_lds16(khB + ((size_t)(kbase + row) << 10) + cl * 8, Kd + tid * 8);
    gload_lds16(vtB + ((size_t)row << 12) + kbase + cl * 8, Vd + tid * 8);
  };

  // prologue: stage Q (128 rows, linear), pp table, first K/V tile
#pragma unroll
  for (int t = 0; t < 2; ++t) {
    int idx = t * 512 + tid;
    int row = idx >> 3, c8 = (idx & 7) * 8;
    gload_lds16(qh + (bsQ + row) * 1024 + h * 64 + c8, QA + idx * 8);
  }
  for (int idx = tid; idx < 576; idx += 512) {
    int r = idx >> 6, d = idx & 63;
    ppS[r * 64 + d] = pp[d * 9 + r];
  }
  stage_kv(k0t * 64, Ks0, Vs0);
  __syncthreads();

  // Q fragments (B-operand): lane holds Q[q = w*16+lr][d = c*32+lg*8+j]
  const int qrowL = w * 16 + lr;
  short8 aq[2];
#pragma unroll
  for (int c = 0; c < 2; ++c)
    aq[c] = *(const short8*)(QA + qrowL * 64 + c * 32 + lg * 8);

  // rel-pos bias (buckets 4..8 only; 0..3 causally dead)
  for (int idx = tid; idx < 640; idx += 512) {
    int row = idx / 5, rr = idx - row * 5;
    const unsigned short* qrow = QA + row * 64;
    const float* pr = ppS + (rr + 4) * 64;
    float s = 0.f;
#pragma unroll
    for (int d8 = 0; d8 < 8; ++d8) {
      short8 qv = *(const short8*)(qrow + d8 * 8);
#pragma unroll
      for (int j = 0; j < 8; ++j)
        s += bf2f((unsigned short)qv[j]) * pr[d8 * 8 + j];
    }
    biasT[row * 6 + rr] = s;
  }
  __syncthreads();

  const float b4 = biasT[qrowL * 6 + 0];
  const float b5 = biasT[qrowL * 6 + 1];
  const float b6 = biasT[qrowL * 6 + 2];
  const float b7 = biasT[qrowL * 6 + 3];
  const float b8 = biasT[qrowL * 6 + 4];
  __syncthreads();  // Q/ppS/biasT dead -> regions A and C recyclable

  const int q_glob = qbase + w * 16 + lr;
  const int wqtop = qbase + w * 16 + 15;  // wave's highest q row
  unsigned short* Pw = Ps + w * 1024;

  float m_run = -1e30f, l_run = 0.f;
  floatx4 o[4] = {};

  for (int kt = k0t; kt < k1t; ++kt) {
    const int kbase = kt * 64;
    const int cur = (kt - k0t) & 1;
    unsigned short* Kc = cur ? Ks1 : Ks0;
    unsigned short* Vc = cur ? Vs1 : Vs0;
    if (kt + 1 < k1t)
      stage_kv(kbase + 64, cur ? Ks0 : Ks1, cur ? Vs0 : Vs1);  // prefetch

    if (kbase <= wqtop) {  // wave has live work in this tile
      // S^T = K @ Q^T : lane holds S[k = kf*16+lg*4+r][q = w*16+lr]
      floatx4 sa[4] = {};
      __builtin_amdgcn_s_setprio(1);
#pragma unroll
      for (int kf = 0; kf < 4; ++kf)
#pragma unroll
        for (int c = 0; c < 2; ++c) {
          int row = kf * 16 + lr;
          short8 ak = *(const short8*)(Kc + row * 64 +
                                       (((c * 4 + lg) ^ (lr & 7)) * 8));
          sa[kf] = __builtin_amdgcn_mfma_f32_16x16x32_bf16(ak, aq[c], sa[kf],
                                                           0, 0, 0);
        }
      __builtin_amdgcn_s_setprio(0);

      // bias + causal mask (registers only)
      float bext;
      if (qbase + w * 16 >= kbase + 67) {
        bext = b8;
      } else {
        bext = 0.f;
#pragma unroll
        for (int kf = 0; kf < 4; ++kf)
#pragma unroll
          for (int r = 0; r < 4; ++r) {
            int dq = q_glob - (kbase + kf * 16 + lg * 4 + r);
            float bb = (dq >= 4) ? b8
                     : (dq == 0 ? b4 : (dq == 1 ? b5 : (dq == 2 ? b6 : b7)));
            sa[kf][r] = (dq < 0) ? -1e30f : (sa[kf][r] + bb);
          }
      }

      // online softmax with defer-max (THR=8)
      float mx = -1e30f;
#pragma unroll
      for (int kf = 0; kf < 4; ++kf)
#pragma unroll
        for (int r = 0; r < 4; ++r) mx = fmaxf(mx, sa[kf][r]);
      mx += bext;
      mx = fmaxf(mx, __shfl_xor(mx, 16, 64));
      mx = fmaxf(mx, __shfl_xor(mx, 32, 64));
      if (__any(mx > m_run + 8.f)) {
        float mn = fmaxf(m_run, mx);
        float al = __builtin_amdgcn_exp2f((m_run - mn) * LOG2E);
        m_run = mn;
        l_run *= al;
        float alo[4];
#pragma unroll
        for (int r = 0; r < 4; ++r) alo[r] = __shfl(al, lg * 4 + r, 64);
#pragma unroll
        for (int df = 0; df < 4; ++df)
#pragma unroll
          for (int r = 0; r < 4; ++r) o[df][r] *= alo[r];
      }

      const float c1 = (bext - m_run) * LOG2E;
      float rs = 0.f;
#pragma unroll
      for (int kf = 0; kf < 4; ++kf) {
        float p0 = __builtin_amdgcn_exp2f(fmaf(sa[kf][0], LOG2E, c1));
        float p1 = __builtin_amdgcn_exp2f(fmaf(sa[kf][1], LOG2E, c1));
        float p2 = __builtin_amdgcn_exp2f(fmaf(sa[kf][2], LOG2E, c1));
        float p3 = __builtin_amdgcn_exp2f(fmaf(sa[kf][3], LOG2E, c1));
        rs += (p0 + p1) + (p2 + p3);
        uint2v pk;
        pk[0] = cvt_pk_bf16(p0, p1);
        pk[1] = cvt_pk_bf16(p2, p3);
        int phys = (kf * 2 + (lg >> 1)) ^ (lr & 7);
        *(uint2v*)(Pw + lr * 64 + phys * 8 + (lg & 1) * 4) = pk;
      }
      rs += __shfl_xor(rs, 16, 64);
      rs += __shfl_xor(rs, 32, 64);
      l_run += rs;

      // O += P @ V
      __builtin_amdgcn_s_setprio(1);
#pragma unroll
      for (int c = 0; c < 2; ++c) {
        short8 pa = *(const short8*)(Pw + lr * 64 +
                                     (((c * 4 + lg) ^ (lr & 7)) * 8));
#pragma unroll
        for (int df = 0; df < 4; ++df) {
          int row = df * 16 + lr;
          short8 bv = *(const short8*)(Vc + row * 64 +
                                       (((c * 4 + lg) ^ (lr & 7)) * 8));
          o[df] = __builtin_amdgcn_mfma_f32_16x16x32_bf16(pa, bv, o[df],
                                                          0, 0, 0);
        }
      }
      __builtin_amdgcn_s_setprio(0);
    }
    __syncthreads();  // drains prefetch vmem + guards buffer swap
  }

  // epilogue: lane holds O[q = w*16+lg*4+r][d = df*16+lr]
  if (!partial) {
    float rl[4];
#pragma unroll
    for (int r = 0; r < 4; ++r)
      rl[r] = __builtin_amdgcn_rcpf(__shfl(l_run, lg * 4 + r, 64));
    const size_t outRow0 = bsQ + w * 16 + lg * 4;
#pragma unroll
    for (int df = 0; df < 4; ++df)
#pragma unroll
      for (int r = 0; r < 4; ++r)
        ao[(outRow0 + r) * 1024 + h * 64 + df * 16 + lr] =
            f2bf(o[df][r] * rl[r]);
  } else {
    const int pid = hb * 32 + pofs;
    unsigned short* op = opart + (size_t)pid * 8192;
#pragma unroll
    for (int df = 0; df < 4; ++df)
#pragma unroll
      for (int r = 0; r < 4; ++r)
        op[(w * 16 + lg * 4 + r) * 64 + df * 16 + lr] = f2bf(o[df][r]);
    if (lg == 0) {
      mbuf[pid * 128 + w * 16 + lr] = m_run;
      lbuf[pid * 128 + w * 16 + lr] = l_run;
    }
  }
}

// ------------------------------ combine partials -----------------------------
__global__ void combine_kern(const unsigned short* __restrict__ opart,
                             const float* __restrict__ mbuf,
                             const float* __restrict__ lbuf,
                             unsigned short* __restrict__ ao) {
  const unsigned char NC[10] = {2, 2, 3, 3, 3, 3, 4, 4, 4, 4};
  const unsigned char PB[10] = {0, 2, 4, 7, 10, 13, 16, 20, 24, 28};
  const int bx = blockIdx.x;        // 0..319
  const int hb = bx / 10, ii = bx - hb * 10;
  const int i = 6 + ii;
  const int b = hb >> 4, h = hb & 15;
  const int nc = NC[ii];
  const int pid0 = hb * 32 + PB[ii];
  const int row = threadIdx.x >> 1;          // 0..127
  const int colg = (threadIdx.x & 1) * 32;   // 0 or 32

  float m[4], l[4];
  float M = -1e30f;
  for (int c = 0; c < nc; ++c) {
    m[c] = mbuf[(pid0 + c) * 128 + row];
    l[c] = lbuf[(pid0 + c) * 128 + row];
    M = fmaxf(M, m[c]);
  }
  float s[4], lsum = 0.f;
  for (int c = 0; c < nc; ++c) {
    s[c] = __builtin_amdgcn_exp2f((m[c] - M) * LOG2E);
    lsum = fmaf(l[c], s[c], lsum);
  }
  const float linv = 1.f / lsum;

  unsigned short* dst =
      ao + ((size_t)b * 2048 + i * 128 + row) * 1024 + h * 64 + colg;
#pragma unroll
  for (int t = 0; t < 4; ++t) {
    float acc[8] = {};
    for (int c = 0; c < nc; ++c) {
      const unsigned short* Oc =
          opart + (size_t)(pid0 + c) * 8192 + row * 64 + colg + t * 8;
      short8 a = *(const short8*)Oc;
#pragma unroll
      for (int j = 0; j < 8; ++j)
        acc[j] = fmaf(bf2f((unsigned short)a[j]), s[c], acc[j]);
    }
    short8 ov;
#pragma unroll
    for (int j = 0; j < 8; ++j) ov[j] = (short)f2bf(acc[j] * linv);
    *(short8*)(dst + t * 8) = ov;
  }
}

// --------------------------------- launcher ---------------------------------
extern "C" void kernel_launch(void* const* d_in, const int* in_sizes, int n_in,
                              void* d_out, int out_size, void* d_ws,
                              size_t ws_size, hipStream_t stream) {
  const float* k_in = (const float*)d_in[0];  // k == v == q (same x tensor)
  const float* Wk = (const float*)d_in[3];
  const float* Wv = (const float*)d_in[4];
  const float* Wq = (const float*)d_in[5];
  const float* Wo = (const float*)d_in[6];
  const float* pp = (const float*)d_in[7];

  const size_t NX = 4096u * 1024u;
  const size_t NW = 1024u * 1024u;
  unsigned short* ws = (unsigned short*)d_ws;
  unsigned short* xbf = ws;
  unsigned short* wkb = xbf + NX;
  unsigned short* wvb = wkb + NW;
  unsigned short* wqb = wvb + NW;
  unsigned short* wob = wqb + NW;
  unsigned short* khb = wob + NW;
  unsigned short* vtb = khb + NX;
  unsigned short* qhb = vtb + NX;
  unsigned short* aob = qhb + NX;
  unsigned short* opart = aob + NX;   // 1024 x 8192 bf16 = 16 MB (ends @64MB)
  // m/l buffers alias the xbf region (dead after proj3): 1024*128 f32 each
  float* mbuf = (float*)xbf;
  float* lbuf = mbuf + 1024 * 128;

  (void)in_sizes; (void)n_in; (void)out_size; (void)ws_size;

  f2bf_all<<<dim3(8192), dim3(256), 0, stream>>>(
      k_in, xbf, Wk, wkb, Wv, wvb, Wq, wqb, Wo, wob);

  proj3_kern<<<dim3(8, 32, 3), dim3(256), 0, stream>>>(
      xbf, wkb, khb, wqb, qhb, wvb, vtb);

  attn_kern<<<dim3(32, 38), dim3(512), 0, stream>>>(qhb, khb, vtb, pp, aob,
                                                    opart, mbuf, lbuf);
  combine_kern<<<dim3(320), dim3(256), 0, stream>>>(opart, mbuf, lbuf, aob);

  gemm_out_kern<<<dim3(8, 64), dim3(256), 0, stream>>>(aob, wob, (float*)d_out);
}

// Round 13
// 101.912 us; speedup vs baseline: 1.4277x; 1.1035x over previous
//
#include <hip/hip_runtime.h>

// ---------------------------------------------------------------------------
// MultiheadAttention (B=2, S=2048, E=1024, H=16, D=64, MAX_DIST=4, causal)
//   1. f2bf_all: one conversion kernel (x once; 4 weights)
//   2. proj3: kh=[bs][e], qh=[bs][e] (*0.125), vt=[e][bs]  (BK=64, swizzled)
//   3. flash attention v11 = r9 4-wave split-K + T14 async-STAGE:
//      K/V staged global->REG (early) -> ds_write (late), raw s_barrier with
//      lgkmcnt(0) only -- no vmcnt(0) drain, prefetch lands under compute.
//   4. combine partials (2-way) -> ao
//   5. out = ao @ Wo^T -> fp32 (64x128 tile, 512 blocks, BK=64)
// ---------------------------------------------------------------------------

using short8  = __attribute__((ext_vector_type(8))) short;
using floatx4 = __attribute__((ext_vector_type(4))) float;
using float4v = __attribute__((ext_vector_type(4))) float;
using ushort4v = __attribute__((ext_vector_type(4))) unsigned short;
using uint2v  = __attribute__((ext_vector_type(2))) unsigned int;

#define LOG2E 1.4426950408889634f

__device__ __forceinline__ unsigned short f2bf(float f) {
  unsigned u = __float_as_uint(f);
  return (unsigned short)((u + 0x7FFFu + ((u >> 16) & 1u)) >> 16);  // RNE
}
__device__ __forceinline__ float bf2f(unsigned short s) {
  return __uint_as_float(((unsigned)s) << 16);
}
__device__ __forceinline__ unsigned cvt_pk_bf16(float lo, float hi) {
  unsigned r;
  asm("v_cvt_pk_bf16_f32 %0, %1, %2" : "=v"(r) : "v"(lo), "v"(hi));
  return r;
}
__device__ __forceinline__ void gload_lds16(const void* g, void* l) {
  __builtin_amdgcn_global_load_lds(
      (const __attribute__((address_space(1))) unsigned int*)g,
      (__attribute__((address_space(3))) unsigned int*)l, 16, 0, 0);
}

// --------------------------- fp32 -> bf16 convert ---------------------------
__global__ void f2bf_all(const float* __restrict__ x, unsigned short* xo,
                         const float* __restrict__ w0, unsigned short* o0,
                         const float* __restrict__ w1, unsigned short* o1,
                         const float* __restrict__ w2, unsigned short* o2,
                         const float* __restrict__ w3, unsigned short* o3) {
  int i = blockIdx.x * 256 + threadIdx.x;  // 0 .. 2M-1 (float4 units)
  const float* in;
  unsigned short* out;
  int off;
  if (i < (1 << 20)) {
    in = x; out = xo; off = i;
  } else {
    int j = i - (1 << 20);
    int s = j >> 18;
    off = j & ((1 << 18) - 1);
    switch (s) {
      case 0: in = w0; out = o0; break;
      case 1: in = w1; out = o1; break;
      case 2: in = w2; out = o2; break;
      default: in = w3; out = o3; break;
    }
  }
  float4v v = ((const float4v*)in)[off];
  ushort4v o;
  o[0] = f2bf(v[0]); o[1] = f2bf(v[1]); o[2] = f2bf(v[2]); o[3] = f2bf(v[3]);
  ((ushort4v*)out)[off] = o;
}

// ------------------------- GEMM core (NT, BK=64, swz) ------------------------
template <int TM>
__device__ __forceinline__ void gemm_core64(
    const unsigned short* __restrict__ A, const unsigned short* __restrict__ B,
    void* __restrict__ Cv, int N, int K, int mBase, int nBase, float alpha,
    bool outbf, unsigned short* As, unsigned short* Bs) {
  const int tid = threadIdx.x;
  const int lane = tid & 63;
  const int w = tid >> 6;
  const int wr = w >> 1, wc = w & 1;
  const int lr = lane & 15, lg = lane >> 4;
  constexpr int NMF = TM / 32;

  floatx4 acc[NMF][4] = {};

  for (int k0 = 0; k0 < K; k0 += 64) {
#pragma unroll
    for (int i = 0; i < TM / 32; ++i) {
      int idx = i * 256 + tid;
      int row = idx >> 3, pc = idx & 7;
      int cl = pc ^ (row & 7);
      gload_lds16(A + (size_t)(mBase + row) * K + k0 + cl * 8, As + idx * 8);
    }
#pragma unroll
    for (int i = 0; i < 4; ++i) {
      int idx = i * 256 + tid;
      int row = idx >> 3, pc = idx & 7;
      int cl = pc ^ (row & 7);
      gload_lds16(B + (size_t)(nBase + row) * K + k0 + cl * 8, Bs + idx * 8);
    }
    __syncthreads();
#pragma unroll
    for (int c = 0; c < 2; ++c) {
      short8 af[NMF], bfr[4];
#pragma unroll
      for (int mf = 0; mf < NMF; ++mf) {
        int row = wr * (TM / 2) + mf * 16 + lr;
        af[mf] = *(const short8*)(As + row * 64 + (((c * 4 + lg) ^ (lr & 7)) * 8));
      }
#pragma unroll
      for (int nf = 0; nf < 4; ++nf) {
        int row = wc * 64 + nf * 16 + lr;
        bfr[nf] = *(const short8*)(Bs + row * 64 + (((c * 4 + lg) ^ (lr & 7)) * 8));
      }
#pragma unroll
      for (int mf = 0; mf < NMF; ++mf)
#pragma unroll
        for (int nf = 0; nf < 4; ++nf)
          acc[mf][nf] = __builtin_amdgcn_mfma_f32_16x16x32_bf16(
              af[mf], bfr[nf], acc[mf][nf], 0, 0, 0);
    }
    __syncthreads();
  }

#pragma unroll
  for (int mf = 0; mf < NMF; ++mf)
#pragma unroll
    for (int nf = 0; nf < 4; ++nf)
#pragma unroll
      for (int r = 0; r < 4; ++r) {
        size_t row = (size_t)mBase + wr * (TM / 2) + mf * 16 + lg * 4 + r;
        size_t col = (size_t)nBase + wc * 64 + nf * 16 + lr;
        float v = acc[mf][nf][r] * alpha;
        if (outbf)
          ((unsigned short*)Cv)[row * (size_t)N + col] = f2bf(v);
        else
          ((float*)Cv)[row * (size_t)N + col] = v;
      }
}

__global__ __launch_bounds__(256, 2) void proj3_kern(
    const unsigned short* __restrict__ xbf, const unsigned short* __restrict__ wkb,
    unsigned short* __restrict__ khb,
    const unsigned short* __restrict__ wqb, unsigned short* __restrict__ qhb,
    const unsigned short* __restrict__ wvb, unsigned short* __restrict__ vtb) {
  __shared__ alignas(16) unsigned short As[128 * 64];
  __shared__ alignas(16) unsigned short Bs[128 * 64];
  int z = blockIdx.z;
  if (z == 0)
    gemm_core64<128>(xbf, wkb, khb, 1024, 1024, blockIdx.y * 128,
                     blockIdx.x * 128, 1.0f, true, As, Bs);
  else if (z == 1)
    gemm_core64<128>(xbf, wqb, qhb, 1024, 1024, blockIdx.y * 128,
                     blockIdx.x * 128, 0.125f, true, As, Bs);
  else
    gemm_core64<128>(wvb, xbf, vtb, 4096, 1024, blockIdx.x * 128,
                     blockIdx.y * 128, 1.0f, true, As, Bs);
}

__global__ __launch_bounds__(256, 2) void gemm_out_kern(
    const unsigned short* __restrict__ A, const unsigned short* __restrict__ B,
    float* __restrict__ C) {
  __shared__ alignas(16) unsigned short As[64 * 64];
  __shared__ alignas(16) unsigned short Bs[128 * 64];
  gemm_core64<64>(A, B, C, 1024, 1024, blockIdx.y * 64, blockIdx.x * 128,
                  1.0f, false, As, Bs);
}

// ---------------------------- flash attention v11 ----------------------------
// Split-K grid (32 hb, 48 units), LPT. 4 waves, each owns 16 q rows.
// T14 async-STAGE: next-next K/V tile -> registers (plain global loads),
// previous regs -> ds_write at step head; step ends with lgkmcnt(0) +
// RAW s_barrier (no vmcnt drain -> loads stay in flight across the barrier).
__global__ __launch_bounds__(256, 4) void attn_kern(
    const unsigned short* __restrict__ qh,   // [4096][1024], pre-scaled
    const unsigned short* __restrict__ kh,   // [4096][1024]
    const unsigned short* __restrict__ vt,   // [1024][4096]
    const float* __restrict__ pp,            // [64][9]
    unsigned short* __restrict__ ao,         // [4096][1024]
    unsigned short* __restrict__ opart,      // [1024][64][64] bf16 unnorm
    float* __restrict__ mbuf,                // [1024][64]
    float* __restrict__ lbuf) {              // [1024][64]
  __shared__ alignas(16) char smem[40960];
  unsigned short* Qs  = (unsigned short*)smem;            // 8K; later K-buf-1
  unsigned short* Vs1 = (unsigned short*)(smem + 8192);   // 8K
  unsigned short* Ks0 = (unsigned short*)(smem + 16384);  // 8K
  unsigned short* Vs0 = (unsigned short*)(smem + 24576);  // 8K
  unsigned short* Ps  = (unsigned short*)(smem + 32768);  // 8K (4 waves x 2K)
  float* ppS   = (float*)(smem + 32768);         // [9][64] f32, prologue only
  float* biasT = (float*)(smem + 35072);         // [64][6] f32, prologue only

  const int tid = threadIdx.x;
  const int lane = tid & 63;
  const int w = tid >> 6;   // 0..3, owns q rows w*16..w*16+15
  const int lr = lane & 15, lg = lane >> 4;
  const int hb = blockIdx.x;
  const int h = hb & 15, b = hb >> 4;
  const int u = blockIdx.y;

  int qt, k0, k1;
  if (u == 0)       { qt = 15;     k0 = 0;  k1 = 16; }
  else if (u <= 16) { qt = 15 + u; k0 = 0;  k1 = 16; }
  else if (u == 17) { qt = 31;     k0 = 16; k1 = 32; }
  else {
    int p = (u - 18) >> 1;
    if (((u - 18) & 1) == 0) { qt = 14 - p; k0 = 0;  k1 = qt + 1; }
    else                     { qt = 30 - p; k0 = 16; k1 = qt + 1; }
  }
  const bool partial = (qt >= 16);
  const int qbase = qt * 64;
  const size_t bsQ = (size_t)b * 2048 + qbase;

  const unsigned short* khB = kh + ((size_t)b * 2048) * 1024 + h * 64;
  const unsigned short* vtB = vt + ((size_t)h * 64) * 4096 + b * 2048;

  // per-thread staging coords (shared by LDS-direct and reg paths)
  const int srow0 = tid >> 3, spc = tid & 7;
  const int scl0 = spc ^ (srow0 & 7);          // pre-swizzled chunk, iter 0
  const int srow1 = srow0 + 32;
  const int scl1 = spc ^ (srow1 & 7);          // iter 1

  auto stage_kv_lds = [&](int kbase, unsigned short* Kd, unsigned short* Vd) {
    gload_lds16(khB + ((size_t)(kbase + srow0) << 10) + scl0 * 8, Kd + tid * 8);
    gload_lds16(vtB + ((size_t)srow0 << 12) + kbase + scl0 * 8, Vd + tid * 8);
    gload_lds16(khB + ((size_t)(kbase + srow1) << 10) + scl1 * 8,
                Kd + (256 + tid) * 8);
    gload_lds16(vtB + ((size_t)srow1 << 12) + kbase + scl1 * 8,
                Vd + (256 + tid) * 8);
  };

  short8 kreg0, kreg1, vreg0, vreg1;  // next-next tile in flight
  auto load_regs = [&](int kbase) {
    kreg0 = *(const short8*)(khB + ((size_t)(kbase + srow0) << 10) + scl0 * 8);
    vreg0 = *(const short8*)(vtB + ((size_t)srow0 << 12) + kbase + scl0 * 8);
    kreg1 = *(const short8*)(khB + ((size_t)(kbase + srow1) << 10) + scl1 * 8);
    vreg1 = *(const short8*)(vtB + ((size_t)srow1 << 12) + kbase + scl1 * 8);
  };
  auto write_regs = [&](unsigned short* Kd, unsigned short* Vd) {
    *(short8*)(Kd + tid * 8) = kreg0;
    *(short8*)(Vd + tid * 8) = vreg0;
    *(short8*)(Kd + (256 + tid) * 8) = kreg1;
    *(short8*)(Vd + (256 + tid) * 8) = vreg1;
  };

  // prologue: stage Q (linear), pp table, first K/V tile (LDS-direct)
#pragma unroll
  for (int i = 0; i < 2; ++i) {
    int idx = i * 256 + tid;
    int row = idx >> 3, c8 = (idx & 7) * 8;
    gload_lds16(qh + (bsQ + row) * 1024 + h * 64 + c8, Qs + idx * 8);
  }
  for (int idx = tid; idx < 576; idx += 256) {
    int r = idx >> 6, d = idx & 63;
    ppS[r * 64 + d] = pp[d * 9 + r];
  }
  stage_kv_lds(k0 * 64, Ks0, Vs0);
  __syncthreads();

  // Q fragments (B-operand): lane holds Q[q = w*16+lr][d = c*32+lg*8+j]
  const int qrowL = w * 16 + lr;
  short8 aq[2];
#pragma unroll
  for (int c = 0; c < 2; ++c)
    aq[c] = *(const short8*)(Qs + qrowL * 64 + c * 32 + lg * 8);

  // rel-pos bias (buckets 4..8 only; 0..3 causally dead)
  for (int idx = tid; idx < 320; idx += 256) {
    int row = idx / 5, rr = idx - row * 5;
    const unsigned short* qrow = Qs + row * 64;
    const float* pr = ppS + (rr + 4) * 64;
    float s = 0.f;
#pragma unroll
    for (int d8 = 0; d8 < 8; ++d8) {
      short8 qv = *(const short8*)(qrow + d8 * 8);
#pragma unroll
      for (int j = 0; j < 8; ++j)
        s += bf2f((unsigned short)qv[j]) * pr[d8 * 8 + j];
    }
    biasT[row * 6 + rr] = s;
  }
  __syncthreads();

  const float b4 = biasT[qrowL * 6 + 0];
  const float b5 = biasT[qrowL * 6 + 1];
  const float b6 = biasT[qrowL * 6 + 2];
  const float b7 = biasT[qrowL * 6 + 3];
  const float b8 = biasT[qrowL * 6 + 4];
  __syncthreads();  // ppS/biasT dead -> Ps free; Qs dead -> K-buf-1

  const int q_glob = qbase + w * 16 + lr;
  unsigned short* Pw = Ps + w * 1024;

  if (k0 + 1 < k1) load_regs((k0 + 1) * 64);  // tile k0+1 -> regs

  float m_run = -1e30f, l_run = 0.f;
  floatx4 o[4] = {};

  for (int kt = k0; kt < k1; ++kt) {
    const int kbase = kt * 64;
    const int cur = (kt - k0) & 1;
    unsigned short* Kc = cur ? Qs : Ks0;
    unsigned short* Vc = cur ? Vs1 : Vs0;

    // phase 1: commit tile kt+1 (regs -> other buffer); safe: that buffer's
    // readers (step kt-1) are behind the previous barrier.
    if (kt + 1 < k1) write_regs(cur ? Ks0 : Qs, cur ? Vs0 : Vs1);
    // phase 2: issue loads for tile kt+2 (land under this step's compute)
    if (kt + 2 < k1) load_regs((kbase + 128));

    // S^T = K @ Q^T : lane holds S[k = kf*16+lg*4+r][q = w*16+lr]
    floatx4 sa[4] = {};
    __builtin_amdgcn_s_setprio(1);
#pragma unroll
    for (int kf = 0; kf < 4; ++kf)
#pragma unroll
      for (int c = 0; c < 2; ++c) {
        int row = kf * 16 + lr;
        short8 ak = *(const short8*)(Kc + row * 64 +
                                     (((c * 4 + lg) ^ (lr & 7)) * 8));
        sa[kf] = __builtin_amdgcn_mfma_f32_16x16x32_bf16(ak, aq[c], sa[kf],
                                                         0, 0, 0);
      }
    __builtin_amdgcn_s_setprio(0);

    // bias + causal mask (registers only)
    float bext;
    if (qbase + w * 16 >= kbase + 67) {
      bext = b8;
    } else {
      bext = 0.f;
#pragma unroll
      for (int kf = 0; kf < 4; ++kf)
#pragma unroll
        for (int r = 0; r < 4; ++r) {
          int dq = q_glob - (kbase + kf * 16 + lg * 4 + r);
          float bb = (dq >= 4) ? b8
                   : (dq == 0 ? b4 : (dq == 1 ? b5 : (dq == 2 ? b6 : b7)));
          sa[kf][r] = (dq < 0) ? -1e30f : (sa[kf][r] + bb);
        }
    }

    // online softmax with defer-max (THR=8)
    float mx = -1e30f;
#pragma unroll
    for (int kf = 0; kf < 4; ++kf)
#pragma unroll
      for (int r = 0; r < 4; ++r) mx = fmaxf(mx, sa[kf][r]);
    mx += bext;
    mx = fmaxf(mx, __shfl_xor(mx, 16, 64));
    mx = fmaxf(mx, __shfl_xor(mx, 32, 64));
    if (__any(mx > m_run + 8.f)) {
      float mn = fmaxf(m_run, mx);
      float al = __builtin_amdgcn_exp2f((m_run - mn) * LOG2E);
      m_run = mn;
      l_run *= al;
      float alo[4];
#pragma unroll
      for (int r = 0; r < 4; ++r) alo[r] = __shfl(al, lg * 4 + r, 64);
#pragma unroll
      for (int df = 0; df < 4; ++df)
#pragma unroll
        for (int r = 0; r < 4; ++r) o[df][r] *= alo[r];
    }

    const float c1 = (bext - m_run) * LOG2E;
    float rs = 0.f;
#pragma unroll
    for (int kf = 0; kf < 4; ++kf) {
      float p0 = __builtin_amdgcn_exp2f(fmaf(sa[kf][0], LOG2E, c1));
      float p1 = __builtin_amdgcn_exp2f(fmaf(sa[kf][1], LOG2E, c1));
      float p2 = __builtin_amdgcn_exp2f(fmaf(sa[kf][2], LOG2E, c1));
      float p3 = __builtin_amdgcn_exp2f(fmaf(sa[kf][3], LOG2E, c1));
      rs += (p0 + p1) + (p2 + p3);
      uint2v pk;
      pk[0] = cvt_pk_bf16(p0, p1);
      pk[1] = cvt_pk_bf16(p2, p3);
      int phys = (kf * 2 + (lg >> 1)) ^ (lr & 7);
      *(uint2v*)(Pw + lr * 64 + phys * 8 + (lg & 1) * 4) = pk;
    }
    rs += __shfl_xor(rs, 16, 64);
    rs += __shfl_xor(rs, 32, 64);
    l_run += rs;

    // O += P @ V
    __builtin_amdgcn_s_setprio(1);
#pragma unroll
    for (int c = 0; c < 2; ++c) {
      short8 pa = *(const short8*)(Pw + lr * 64 +
                                   (((c * 4 + lg) ^ (lr & 7)) * 8));
#pragma unroll
      for (int df = 0; df < 4; ++df) {
        int row = df * 16 + lr;
        short8 bv = *(const short8*)(Vc + row * 64 +
                                     (((c * 4 + lg) ^ (lr & 7)) * 8));
        o[df] = __builtin_amdgcn_mfma_f32_16x16x32_bf16(pa, bv, o[df],
                                                        0, 0, 0);
      }
    }
    __builtin_amdgcn_s_setprio(0);

    // raw barrier: ds ops drained (lgkmcnt), vmem loads STAY IN FLIGHT
    asm volatile("s_waitcnt lgkmcnt(0)" ::: "memory");
    __builtin_amdgcn_s_barrier();
  }

  // epilogue: lane holds O[q = w*16+lg*4+r][d = df*16+lr]
  if (!partial) {
    float rl[4];
#pragma unroll
    for (int r = 0; r < 4; ++r)
      rl[r] = __builtin_amdgcn_rcpf(__shfl(l_run, lg * 4 + r, 64));
    const size_t outRow0 = bsQ + w * 16 + lg * 4;
#pragma unroll
    for (int df = 0; df < 4; ++df)
#pragma unroll
      for (int r = 0; r < 4; ++r)
        ao[(outRow0 + r) * 1024 + h * 64 + df * 16 + lr] =
            f2bf(o[df][r] * rl[r]);
  } else {
    const int pid = (hb * 16 + (qt - 16)) * 2 + (k0 == 16 ? 1 : 0);
    unsigned short* op = opart + (size_t)pid * 4096;
#pragma unroll
    for (int df = 0; df < 4; ++df)
#pragma unroll
      for (int r = 0; r < 4; ++r)
        op[(w * 16 + lg * 4 + r) * 64 + df * 16 + lr] = f2bf(o[df][r]);
    if (lg == 0) {
      mbuf[pid * 64 + w * 16 + lr] = m_run;
      lbuf[pid * 64 + w * 16 + lr] = l_run;
    }
  }
}

// ------------------------------ combine partials -----------------------------
__global__ void combine_kern(const unsigned short* __restrict__ opart,
                             const float* __restrict__ mbuf,
                             const float* __restrict__ lbuf,
                             unsigned short* __restrict__ ao) {
  const int t = blockIdx.x;         // 0..511
  const int hb = t >> 4;
  const int qtl = t & 15;
  const int qt = 16 + qtl;
  const int b = hb >> 4, h = hb & 15;
  const int pid0 = (hb * 16 + qtl) * 2, pid1 = pid0 + 1;
  const int row = threadIdx.x >> 2;
  const int colg = (threadIdx.x & 3) * 16;

  float m1 = mbuf[pid0 * 64 + row], m2 = mbuf[pid1 * 64 + row];
  float l1 = lbuf[pid0 * 64 + row], l2 = lbuf[pid1 * 64 + row];
  float m = fmaxf(m1, m2);
  float s1 = __builtin_amdgcn_exp2f((m1 - m) * LOG2E);
  float s2 = __builtin_amdgcn_exp2f((m2 - m) * LOG2E);
  float linv = 1.f / fmaf(l1, s1, l2 * s2);
  s1 *= linv; s2 *= linv;

  const unsigned short* O1 = opart + (size_t)pid0 * 4096 + row * 64 + colg;
  const unsigned short* O2 = opart + (size_t)pid1 * 4096 + row * 64 + colg;
  unsigned short* dst =
      ao + ((size_t)b * 2048 + qt * 64 + row) * 1024 + h * 64 + colg;
#pragma unroll
  for (int i = 0; i < 2; ++i) {
    short8 a = *(const short8*)(O1 + i * 8);
    short8 c = *(const short8*)(O2 + i * 8);
    short8 ov;
#pragma unroll
    for (int j = 0; j < 8; ++j)
      ov[j] = (short)f2bf(fmaf(bf2f((unsigned short)a[j]), s1,
                               bf2f((unsigned short)c[j]) * s2));
    *(short8*)(dst + i * 8) = ov;
  }
}

// --------------------------------- launcher ---------------------------------
extern "C" void kernel_launch(void* const* d_in, const int* in_sizes, int n_in,
                              void* d_out, int out_size, void* d_ws,
                              size_t ws_size, hipStream_t stream) {
  const float* k_in = (const float*)d_in[0];  // k == v == q (same x tensor)
  const float* Wk = (const float*)d_in[3];
  const float* Wv = (const float*)d_in[4];
  const float* Wq = (const float*)d_in[5];
  const float* Wo = (const float*)d_in[6];
  const float* pp = (const float*)d_in[7];

  const size_t NX = 4096u * 1024u;
  const size_t NW = 1024u * 1024u;
  unsigned short* ws = (unsigned short*)d_ws;
  unsigned short* xbf = ws;
  unsigned short* wkb = xbf + NX;
  unsigned short* wvb = wkb + NW;
  unsigned short* wqb = wvb + NW;
  unsigned short* wob = wqb + NW;
  unsigned short* khb = wob + NW;
  unsigned short* vtb = khb + NX;
  unsigned short* qhb = vtb + NX;
  unsigned short* aob = qhb + NX;
  unsigned short* opart = aob + NX;          // 1024 tiles x 4096 bf16 = 8 MB
  float* mbuf = (float*)(opart + NX);        // 1024*64 f32
  float* lbuf = mbuf + 1024 * 64;

  (void)in_sizes; (void)n_in; (void)out_size; (void)ws_size;

  f2bf_all<<<dim3(8192), dim3(256), 0, stream>>>(
      k_in, xbf, Wk, wkb, Wv, wvb, Wq, wqb, Wo, wob);

  proj3_kern<<<dim3(8, 32, 3), dim3(256), 0, stream>>>(
      xbf, wkb, khb, wqb, qhb, wvb, vtb);

  attn_kern<<<dim3(32, 48), dim3(256), 0, stream>>>(qhb, khb, vtb, pp, aob,
                                                    opart, mbuf, lbuf);
  combine_kern<<<dim3(512), dim3(256), 0, stream>>>(opart, mbuf, lbuf, aob);

  gemm_out_kern<<<dim3(8, 64), dim3(256), 0, stream>>>(aob, wob, (float*)d_out);
}